// Round 4
// baseline (314.855 us; speedup 1.0000x reference)
//
#include <hip/hip_runtime.h>
#include <hip/hip_bf16.h>

typedef __attribute__((ext_vector_type(8))) short  short8;
typedef __attribute__((ext_vector_type(4))) float  floatx4;

#define UH   2048    // U * H (row stride of inputs/hidden/out in floats)
#define XPAD 264     // 256 + 8 bf16 pad (528 B row stride, 16B aligned)

#define MFMA16(a,b,c) __builtin_amdgcn_mfma_f32_16x16x32_bf16(a, b, c, 0, 0, 0)

static __device__ __forceinline__ unsigned int pkbf16(float a, float b) {
    __hip_bfloat162 p = __float22bfloat162_rn(make_float2(a, b));
    return *(unsigned int*)&p;
}

// ---------------- prep kernel (round-0 proven) --------------------------------
// Wc in MFMA-fragment order: fragment id = (u*24 + gt)*8 + s  (gt = 16-gate tile,
// s = k-step). Element lane*8+j = W[u][gt*16+(lane&15)][s*32+(lane>>4)*8+j],
// k<128 -> w_ih, else w_hh.
// blocks [0,768): weights; [768,800): bias_c[u][512]
__global__ __launch_bounds__(256) void prep(const float* __restrict__ w_ih,
                                            const float* __restrict__ w_hh,
                                            const float* __restrict__ b_ih,
                                            const float* __restrict__ b_hh,
                                            __hip_bfloat16* __restrict__ Wc,
                                            float* __restrict__ bias_c) {
    if (blockIdx.x < 768) {
        int t   = blockIdx.x * 256 + threadIdx.x;   // [0, 196608)
        int k8  = t & 31;                           // 8-float chunk within row
        int row = t >> 5;                           // u*384 + g
        int u   = row / 384;
        int g   = row - u * 384;
        int k   = k8 * 8;
        const float* src = (k < 128) ? (w_ih + (size_t)row * 128 + k)
                                     : (w_hh + (size_t)row * 128 + (k - 128));
        float4 v0 = ((const float4*)src)[0];
        float4 v1 = ((const float4*)src)[1];
        uint4 w;
        w.x = pkbf16(v0.x, v0.y);
        w.y = pkbf16(v0.z, v0.w);
        w.z = pkbf16(v1.x, v1.y);
        w.w = pkbf16(v1.z, v1.w);
        int gt = g >> 4, lr = g & 15;
        int s  = k8 >> 2, lq = k8 & 3;
        size_t off = (size_t)((u * 24 + gt) * 8 + s) * 512 + (lq * 16 + lr) * 8;
        *(uint4*)(Wc + off) = w;
    } else {
        int idx = (blockIdx.x - 768) * 256 + threadIdx.x;   // [0, 8192)
        int u = idx >> 9;
        int g = idx & 511;
        float v;
        if (g < 256)       v = b_ih[u * 384 + g] + b_hh[u * 384 + g];
        else if (g < 384)  v = b_ih[u * 384 + g];          // xn bias
        else               v = b_hh[u * 384 + (g - 128)];  // hn bias
        bias_c[idx] = v;
    }
}

// ---------------- fused GRU kernel --------------------------------------------
// 1024 blocks x 512 threads, ALL resident: 4 blocks/CU (LDS 4x33.8KB = 135KB,
// VGPR <= 128 via launch_bounds(512,4)). 32-row double-buffered tiles; W frags
// streamed from L2-resident Wc per s-step (no register hoard -> occupancy).
// Swapped-D MFMA (A=W, B=X): lane l, reg r -> row m = (l&15)+16*m4,
// col c = (l>>4)*4 + r + 16*wv  => float4 coalesced stores, bias in acc init.
// Epilogue runs post-barrier (overlaps next tile's LDS+MFMA across waves);
// hv read from global fp32 hidden (no LDS race, better accuracy).
__global__ __launch_bounds__(512, 4) void gru_fused(
    const float* __restrict__ inputs, const float* __restrict__ hidden,
    const __hip_bfloat16* __restrict__ Wc, const float* __restrict__ bias_c,
    float* __restrict__ out)
{
    __shared__ __align__(16) __hip_bfloat16 Xs[2][32][XPAD];

    const int bx   = blockIdx.x;                        // [0,1024)
    const int u    = ((bx & 7) << 1) | ((bx >> 3) & 1); // XCD-local u pair
    const int r0   = (bx >> 4) * 128;                   // 4 tiles of 32 rows
    const int tid  = threadIdx.x;
    const int lane = tid & 63;
    const int wv   = tid >> 6;      // [0,8): wave owns output cols [16*wv,16*wv+16)
    const int lr   = lane & 15;
    const int lq   = lane >> 4;

    // ---- bias -> accumulator init (thread covers cols c0..c0+3) -------------
    const int c0 = wv * 16 + lq * 4;
    const floatx4 accR0  = *(const floatx4*)(bias_c + u * 512 +       c0);
    const floatx4 accZ0  = *(const floatx4*)(bias_c + u * 512 + 128 + c0);
    const floatx4 accXN0 = *(const floatx4*)(bias_c + u * 512 + 256 + c0);
    const floatx4 accHN0 = *(const floatx4*)(bias_c + u * 512 + 384 + c0);

    // ---- staging: thread loads 16B at col scol for rows 8i+wv ---------------
    const int scol = lane * 4;                          // float col in [0,256)
    const float* sbase = ((scol < 128) ? (inputs + scol)
                                       : (hidden + (scol - 128)))
                       + (size_t)u * 128;

    float4 stg[4];   // in-flight half-tile (16 VGPR)

    auto ISSUE = [&](int rowbase) {
        #pragma unroll
        for (int i = 0; i < 4; ++i)
            stg[i] = *(const float4*)(sbase + (size_t)(rowbase + i * 8 + wv) * UH);
    };
    auto WRITE = [&](int buf) {
        #pragma unroll
        for (int i = 0; i < 4; ++i) {
            uint2 w;
            w.x = pkbf16(stg[i].x, stg[i].y);
            w.y = pkbf16(stg[i].z, stg[i].w);
            *(uint2*)&Xs[buf][i * 8 + wv][scol] = w;
        }
    };
    auto BARRIER = [&]() {
        // drain LDS only; global prefetch loads stay in flight across barrier
        asm volatile("s_waitcnt lgkmcnt(0)" ::: "memory");
        __builtin_amdgcn_sched_barrier(0);
        __builtin_amdgcn_s_barrier();
        __builtin_amdgcn_sched_barrier(0);
    };

    // W fragment base for this u + lane's 16B slot (bf16, MFMA-fragment order)
    const short* WgU = (const short*)Wc + (size_t)u * 98304 + lane * 8;

    // ---- prologue -----------------------------------------------------------
    ISSUE(r0);
    WRITE(0);
    ISSUE(r0 + 32);
    BARRIER();

    #pragma unroll 1
    for (int j = 0; j < 4; ++j) {
        const int buf = j & 1;

        // ---- compute tile j: stream W frags from L2, X frags from LDS -------
        floatx4 aR[2]  = {accR0,  accR0};
        floatx4 aZ[2]  = {accZ0,  accZ0};
        floatx4 aXN[2] = {accXN0, accXN0};
        floatx4 aHN[2] = {accHN0, accHN0};
        #pragma unroll
        for (int s = 0; s < 8; ++s) {
            short8 bR = *(const short8*)(WgU + (size_t)(      wv * 8 + s) * 512);
            short8 bZ = *(const short8*)(WgU + (size_t)( 64 + wv * 8 + s) * 512);
            short8 bN = *(const short8*)(WgU + (size_t)(128 + wv * 8 + s) * 512);
            #pragma unroll
            for (int m4 = 0; m4 < 2; ++m4) {
                short8 xF = *(const short8*)((const short*)&Xs[buf][m4 * 16 + lr][0]
                                             + s * 32 + lq * 8);
                aR[m4] = MFMA16(bR, xF, aR[m4]);
                aZ[m4] = MFMA16(bZ, xF, aZ[m4]);
                if (s < 4) aXN[m4] = MFMA16(bN, xF, aXN[m4]);
                else       aHN[m4] = MFMA16(bN, xF, aHN[m4]);
            }
        }

        // ---- pipeline: land tile j+1, launch tile j+2, release the barrier --
        if (j < 3) {
            WRITE(buf ^ 1);                       // waits only its own stg vmcnt
            if (j < 2) ISSUE(r0 + (j + 2) * 32);  // fire-and-forget
            BARRIER();
        }

        // ---- epilogue (post-barrier, regs + global only: overlaps next tile)
        const int rowb = r0 + j * 32;
        #pragma unroll
        for (int m4 = 0; m4 < 2; ++m4) {
            const int m = rowb + m4 * 16 + lr;
            float4 hq = *(const float4*)(hidden + (size_t)m * UH + u * 128 + c0);
            const float hs[4] = {hq.x, hq.y, hq.z, hq.w};
            float4 o;
            float* op = (float*)&o;
            #pragma unroll
            for (int r = 0; r < 4; ++r) {
                float rv = __builtin_amdgcn_rcpf(1.f + __expf(-aR[m4][r]));
                float zv = __builtin_amdgcn_rcpf(1.f + __expf(-aZ[m4][r]));
                float npre = aXN[m4][r] + rv * aHN[m4][r];
                float nv = 2.f * __builtin_amdgcn_rcpf(1.f + __expf(-2.f * npre)) - 1.f; // tanh
                op[r] = nv + zv * (hs[r] - nv);
            }
            *(float4*)(out + (size_t)m * UH + u * 128 + c0) = o;
        }
    }
}

// ---------------- launch ------------------------------------------------------

extern "C" void kernel_launch(void* const* d_in, const int* in_sizes, int n_in,
                              void* d_out, int out_size, void* d_ws, size_t ws_size,
                              hipStream_t stream) {
    const float* inputs = (const float*)d_in[0];
    const float* hidden = (const float*)d_in[1];
    const float* w_ih   = (const float*)d_in[2];
    const float* w_hh   = (const float*)d_in[3];
    const float* b_ih   = (const float*)d_in[4];
    const float* b_hh   = (const float*)d_in[5];
    float* out = (float*)d_out;

    __hip_bfloat16* Wc = (__hip_bfloat16*)d_ws;
    float* bias_c = (float*)((char*)d_ws + (size_t)16 * 384 * 256 * 2);  // +3,145,728 B

    prep<<<dim3(800), dim3(256), 0, stream>>>(w_ih, w_hh, b_ih, b_hh, Wc, bias_c);
    gru_fused<<<dim3(1024), dim3(512), 0, stream>>>(inputs, hidden, Wc, bias_c, out);
}

// Round 5
// 291.687 us; speedup vs baseline: 1.0794x; 1.0794x over previous
//
#include <hip/hip_runtime.h>
#include <hip/hip_bf16.h>

typedef __attribute__((ext_vector_type(8))) short  short8;
typedef __attribute__((ext_vector_type(4))) float  floatx4;

#define UH   2048    // U * H (row stride of inputs/hidden/out in floats)
#define XPAD 264     // 256 + 8 bf16 pad (528 B row stride, 16B aligned)

#define MFMA16(a,b,c) __builtin_amdgcn_mfma_f32_16x16x32_bf16(a, b, c, 0, 0, 0)

static __device__ __forceinline__ unsigned int pkbf16(float a, float b) {
    __hip_bfloat162 p = __float22bfloat162_rn(make_float2(a, b));
    return *(unsigned int*)&p;
}
static __device__ __forceinline__ float bf2f(unsigned short h) {
    unsigned int u = (unsigned int)h << 16;
    return *(float*)&u;
}

// ---------------- prep kernel (round-0 proven) --------------------------------
// Wc in MFMA-fragment order: fragment id = (u*24 + gt)*8 + s  (gt = 16-gate tile,
// s = k-step). Element lane*8+j = W[u][gt*16+(lane&15)][s*32+(lane>>4)*8+j],
// k<128 -> w_ih, else w_hh.
// blocks [0,768): weights; [768,800): bias_c[u][512]
__global__ __launch_bounds__(256) void prep(const float* __restrict__ w_ih,
                                            const float* __restrict__ w_hh,
                                            const float* __restrict__ b_ih,
                                            const float* __restrict__ b_hh,
                                            __hip_bfloat16* __restrict__ Wc,
                                            float* __restrict__ bias_c) {
    if (blockIdx.x < 768) {
        int t   = blockIdx.x * 256 + threadIdx.x;   // [0, 196608)
        int k8  = t & 31;                           // 8-float chunk within row
        int row = t >> 5;                           // u*384 + g
        int u   = row / 384;
        int g   = row - u * 384;
        int k   = k8 * 8;
        const float* src = (k < 128) ? (w_ih + (size_t)row * 128 + k)
                                     : (w_hh + (size_t)row * 128 + (k - 128));
        float4 v0 = ((const float4*)src)[0];
        float4 v1 = ((const float4*)src)[1];
        uint4 w;
        w.x = pkbf16(v0.x, v0.y);
        w.y = pkbf16(v0.z, v0.w);
        w.z = pkbf16(v1.x, v1.y);
        w.w = pkbf16(v1.z, v1.w);
        int gt = g >> 4, lr = g & 15;
        int s  = k8 >> 2, lq = k8 & 3;
        size_t off = (size_t)((u * 24 + gt) * 8 + s) * 512 + (lq * 16 + lr) * 8;
        *(uint4*)(Wc + off) = w;
    } else {
        int idx = (blockIdx.x - 768) * 256 + threadIdx.x;   // [0, 8192)
        int u = idx >> 9;
        int g = idx & 511;
        float v;
        if (g < 256)       v = b_ih[u * 384 + g] + b_hh[u * 384 + g];
        else if (g < 384)  v = b_ih[u * 384 + g];          // xn bias
        else               v = b_hh[u * 384 + (g - 128)];  // hn bias
        bias_c[idx] = v;
    }
}

// ---------------- fused GRU kernel --------------------------------------------
// 1024 blocks x 512 threads, ALL resident: 4 blocks/CU (LDS 4x33.8KB = 135KB,
// VGPR 64). 32-row double-buffered tiles; W frags streamed from L2-resident Wc.
// Swapped-D MFMA (A=W, B=X): lane l, reg r -> row m = (l&15)+16*m4,
// col c = (l>>4)*4 + r + 16*wv  => float4 coalesced stores, bias in acc init.
// Epilogue PRE-barrier (r3-proven ordering, race-free) with hv read from the
// LDS tile (bf16) — NO global hidden re-read. Round 4 showed the extra global
// stream thrashes L3/L2 and amplifies partial-line out writebacks 4.3x; this
// reverts traffic to the r0-r3 clean profile while keeping r4's occupancy.
__global__ __launch_bounds__(512, 4) void gru_fused(
    const float* __restrict__ inputs, const float* __restrict__ hidden,
    const __hip_bfloat16* __restrict__ Wc, const float* __restrict__ bias_c,
    float* __restrict__ out)
{
    __shared__ __align__(16) __hip_bfloat16 Xs[2][32][XPAD];

    const int bx   = blockIdx.x;                        // [0,1024)
    const int u    = ((bx & 7) << 1) | ((bx >> 3) & 1); // XCD-local u pair
    const int r0   = (bx >> 4) * 128;                   // 4 tiles of 32 rows
    const int tid  = threadIdx.x;
    const int lane = tid & 63;
    const int wv   = tid >> 6;      // [0,8): wave owns output cols [16*wv,16*wv+16)
    const int lr   = lane & 15;
    const int lq   = lane >> 4;

    // ---- bias -> accumulator init (thread covers cols c0..c0+3) -------------
    const int c0 = wv * 16 + lq * 4;
    const floatx4 accR0  = *(const floatx4*)(bias_c + u * 512 +       c0);
    const floatx4 accZ0  = *(const floatx4*)(bias_c + u * 512 + 128 + c0);
    const floatx4 accXN0 = *(const floatx4*)(bias_c + u * 512 + 256 + c0);
    const floatx4 accHN0 = *(const floatx4*)(bias_c + u * 512 + 384 + c0);

    // ---- staging: thread loads 16B at col scol for rows 8i+wv ---------------
    const int scol = lane * 4;                          // float col in [0,256)
    const float* sbase = ((scol < 128) ? (inputs + scol)
                                       : (hidden + (scol - 128)))
                       + (size_t)u * 128;

    float4 stg[4];   // in-flight half-tile (16 VGPR)

    auto ISSUE = [&](int rowbase) {
        #pragma unroll
        for (int i = 0; i < 4; ++i)
            stg[i] = *(const float4*)(sbase + (size_t)(rowbase + i * 8 + wv) * UH);
    };
    auto WRITE = [&](int buf) {
        #pragma unroll
        for (int i = 0; i < 4; ++i) {
            uint2 w;
            w.x = pkbf16(stg[i].x, stg[i].y);
            w.y = pkbf16(stg[i].z, stg[i].w);
            *(uint2*)&Xs[buf][i * 8 + wv][scol] = w;
        }
    };
    auto BARRIER = [&]() {
        // drain LDS only; global prefetch loads stay in flight across barrier
        asm volatile("s_waitcnt lgkmcnt(0)" ::: "memory");
        __builtin_amdgcn_sched_barrier(0);
        __builtin_amdgcn_s_barrier();
        __builtin_amdgcn_sched_barrier(0);
    };

    // W fragment base for this u + lane's 16B slot (bf16, MFMA-fragment order)
    const short* WgU = (const short*)Wc + (size_t)u * 98304 + lane * 8;

    // ---- prologue -----------------------------------------------------------
    ISSUE(r0);
    WRITE(0);
    ISSUE(r0 + 32);
    BARRIER();

    #pragma unroll 1
    for (int j = 0; j < 4; ++j) {
        const int buf = j & 1;

        // ---- compute tile j: stream W frags from L2, X frags from LDS -------
        floatx4 aR[2]  = {accR0,  accR0};
        floatx4 aZ[2]  = {accZ0,  accZ0};
        floatx4 aXN[2] = {accXN0, accXN0};
        floatx4 aHN[2] = {accHN0, accHN0};
        #pragma unroll
        for (int s = 0; s < 8; ++s) {
            short8 bR = *(const short8*)(WgU + (size_t)(      wv * 8 + s) * 512);
            short8 bZ = *(const short8*)(WgU + (size_t)( 64 + wv * 8 + s) * 512);
            short8 bN = *(const short8*)(WgU + (size_t)(128 + wv * 8 + s) * 512);
            #pragma unroll
            for (int m4 = 0; m4 < 2; ++m4) {
                short8 xF = *(const short8*)((const short*)&Xs[buf][m4 * 16 + lr][0]
                                             + s * 32 + lq * 8);
                aR[m4] = MFMA16(bR, xF, aR[m4]);
                aZ[m4] = MFMA16(bZ, xF, aZ[m4]);
                if (s < 4) aXN[m4] = MFMA16(bN, xF, aXN[m4]);
                else       aHN[m4] = MFMA16(bN, xF, aHN[m4]);
            }
        }

        // ---- pipeline: land tile j+1, launch tile j+2 (fly under epilogue) --
        if (j < 3) {
            WRITE(buf ^ 1);                       // waits only its own stg vmcnt
            if (j < 2) ISSUE(r0 + (j + 2) * 32);  // fire-and-forget
        }

        // ---- epilogue (pre-barrier, hv from LDS tile — r3-proven, race-free)
        const int rowb = r0 + j * 32;
        #pragma unroll
        for (int m4 = 0; m4 < 2; ++m4) {
            const int mloc = m4 * 16 + lr;
            ushort4 hq = *(const ushort4*)&Xs[buf][mloc][128 + c0];
            const unsigned short hs[4] = {hq.x, hq.y, hq.z, hq.w};
            float4 o;
            float* op = (float*)&o;
            #pragma unroll
            for (int r = 0; r < 4; ++r) {
                float rv = __builtin_amdgcn_rcpf(1.f + __expf(-aR[m4][r]));
                float zv = __builtin_amdgcn_rcpf(1.f + __expf(-aZ[m4][r]));
                float npre = aXN[m4][r] + rv * aHN[m4][r];
                float nv = 2.f * __builtin_amdgcn_rcpf(1.f + __expf(-2.f * npre)) - 1.f; // tanh
                float hv = bf2f(hs[r]);          // original hidden (bf16, from LDS)
                op[r] = nv + zv * (hv - nv);
            }
            *(float4*)(out + (size_t)(rowb + mloc) * UH + u * 128 + c0) = o;
        }

        if (j < 3) BARRIER();
    }
}

// ---------------- launch ------------------------------------------------------

extern "C" void kernel_launch(void* const* d_in, const int* in_sizes, int n_in,
                              void* d_out, int out_size, void* d_ws, size_t ws_size,
                              hipStream_t stream) {
    const float* inputs = (const float*)d_in[0];
    const float* hidden = (const float*)d_in[1];
    const float* w_ih   = (const float*)d_in[2];
    const float* w_hh   = (const float*)d_in[3];
    const float* b_ih   = (const float*)d_in[4];
    const float* b_hh   = (const float*)d_in[5];
    float* out = (float*)d_out;

    __hip_bfloat16* Wc = (__hip_bfloat16*)d_ws;
    float* bias_c = (float*)((char*)d_ws + (size_t)16 * 384 * 256 * 2);  // +3,145,728 B

    prep<<<dim3(800), dim3(256), 0, stream>>>(w_ih, w_hh, b_ih, b_hh, Wc, bias_c);
    gru_fused<<<dim3(1024), dim3(512), 0, stream>>>(inputs, hidden, Wc, bias_c, out);
}

// Round 7
// 271.970 us; speedup vs baseline: 1.1577x; 1.0725x over previous
//
#include <hip/hip_runtime.h>
#include <hip/hip_bf16.h>

typedef __attribute__((ext_vector_type(8))) short  short8;
typedef __attribute__((ext_vector_type(4))) float  floatx4;

#define UH   2048    // U * H (row stride of inputs/hidden/out in floats)
#define XPAD 264     // 256 + 8 bf16 pad (528 B row stride, 16B aligned)
#define FPAD 132     // fp32 view of an Xs row: 132 floats = 528 B

#define MFMA16(a,b,c) __builtin_amdgcn_mfma_f32_16x16x32_bf16(a, b, c, 0, 0, 0)

static __device__ __forceinline__ unsigned int pkbf16(float a, float b) {
    __hip_bfloat162 p = __float22bfloat162_rn(make_float2(a, b));
    return *(unsigned int*)&p;
}
static __device__ __forceinline__ float bf2f(unsigned short h) {
    unsigned int u = (unsigned int)h << 16;
    return *(float*)&u;
}

// ---------------- prep kernel (round-0 proven) --------------------------------
// Wc in MFMA-fragment order: fragment id = (u*24 + gt)*8 + s  (gt = 16-gate tile,
// s = k-step). Element lane*8+j = W[u][gt*16+(lane&15)][s*32+(lane>>4)*8+j],
// k<128 -> w_ih, else w_hh.
// blocks [0,768): weights; [768,800): bias_c[u][512]
__global__ __launch_bounds__(256) void prep(const float* __restrict__ w_ih,
                                            const float* __restrict__ w_hh,
                                            const float* __restrict__ b_ih,
                                            const float* __restrict__ b_hh,
                                            __hip_bfloat16* __restrict__ Wc,
                                            float* __restrict__ bias_c) {
    if (blockIdx.x < 768) {
        int t   = blockIdx.x * 256 + threadIdx.x;   // [0, 196608)
        int k8  = t & 31;                           // 8-float chunk within row
        int row = t >> 5;                           // u*384 + g
        int u   = row / 384;
        int g   = row - u * 384;
        int k   = k8 * 8;
        const float* src = (k < 128) ? (w_ih + (size_t)row * 128 + k)
                                     : (w_hh + (size_t)row * 128 + (k - 128));
        float4 v0 = ((const float4*)src)[0];
        float4 v1 = ((const float4*)src)[1];
        uint4 w;
        w.x = pkbf16(v0.x, v0.y);
        w.y = pkbf16(v0.z, v0.w);
        w.z = pkbf16(v1.x, v1.y);
        w.w = pkbf16(v1.z, v1.w);
        int gt = g >> 4, lr = g & 15;
        int s  = k8 >> 2, lq = k8 & 3;
        size_t off = (size_t)((u * 24 + gt) * 8 + s) * 512 + (lq * 16 + lr) * 8;
        *(uint4*)(Wc + off) = w;
    } else {
        int idx = (blockIdx.x - 768) * 256 + threadIdx.x;   // [0, 8192)
        int u = idx >> 9;
        int g = idx & 511;
        float v;
        if (g < 256)       v = b_ih[u * 384 + g] + b_hh[u * 384 + g];
        else if (g < 384)  v = b_ih[u * 384 + g];          // xn bias
        else               v = b_hh[u * 384 + (g - 128)];  // hn bias
        bias_c[idx] = v;
    }
}

// ---------------- fused GRU kernel --------------------------------------------
// 1024 blocks x 512 threads, 4 blocks/CU (LDS 4x33.8KB, VGPR<=128). 32-row
// double-buffered tiles; W frags streamed from L2-resident Wc (u paired per XCD).
//
// WRITE-AMPLIFICATION FIX (r4/r5 showed 4.2x HBM write traffic): the MFMA
// accumulator layout gives each wave only 64B per 128B out line; under 4-block
// interleave the line is evicted between the two waves' halves -> write-allocate
// refetch + double partial writeback. Now the fp32 results BOUNCE through the
// dead Xs[buf] (fp32 view [32][132]) and a store pass writes each out row as a
// contiguous 512B wave burst: every store covers full 128B lines regardless of
// scheduling. Staging loads + out stores are non-temporal (read/write-once) so
// they don't thrash the L2 that Wc needs.
__global__ __launch_bounds__(512, 4) void gru_fused(
    const float* __restrict__ inputs, const float* __restrict__ hidden,
    const __hip_bfloat16* __restrict__ Wc, const float* __restrict__ bias_c,
    float* __restrict__ out)
{
    __shared__ __align__(16) __hip_bfloat16 Xs[2][32][XPAD];

    const int bx   = blockIdx.x;                        // [0,1024)
    const int u    = ((bx & 7) << 1) | ((bx >> 3) & 1); // XCD-local u pair
    const int r0   = (bx >> 4) * 128;                   // 4 tiles of 32 rows
    const int tid  = threadIdx.x;
    const int lane = tid & 63;
    const int wv   = tid >> 6;      // [0,8): wave owns output cols [16*wv,16*wv+16)
    const int lr   = lane & 15;
    const int lq   = lane >> 4;

    // ---- bias -> accumulator init (thread covers cols c0..c0+3) -------------
    const int c0 = wv * 16 + lq * 4;
    const floatx4 accR0  = *(const floatx4*)(bias_c + u * 512 +       c0);
    const floatx4 accZ0  = *(const floatx4*)(bias_c + u * 512 + 128 + c0);
    const floatx4 accXN0 = *(const floatx4*)(bias_c + u * 512 + 256 + c0);
    const floatx4 accHN0 = *(const floatx4*)(bias_c + u * 512 + 384 + c0);

    // ---- staging: thread loads 16B at col scol for rows 8i+wv ---------------
    const int scol = lane * 4;                          // float col in [0,256)
    const float* sbase = ((scol < 128) ? (inputs + scol)
                                       : (hidden + (scol - 128)))
                       + (size_t)u * 128;

    floatx4 stg[4];   // in-flight half-tile (16 VGPR)

    auto ISSUE = [&](int rowbase) {
        #pragma unroll
        for (int i = 0; i < 4; ++i)
            stg[i] = __builtin_nontemporal_load(
                (const floatx4*)(sbase + (size_t)(rowbase + i * 8 + wv) * UH));
    };
    auto WRITE = [&](int buf) {
        #pragma unroll
        for (int i = 0; i < 4; ++i) {
            uint2 w;
            w.x = pkbf16(stg[i][0], stg[i][1]);
            w.y = pkbf16(stg[i][2], stg[i][3]);
            *(uint2*)&Xs[buf][i * 8 + wv][scol] = w;
        }
    };
    auto BARRIER = [&]() {
        // drain LDS only; global prefetch loads stay in flight across barrier
        asm volatile("s_waitcnt lgkmcnt(0)" ::: "memory");
        __builtin_amdgcn_sched_barrier(0);
        __builtin_amdgcn_s_barrier();
        __builtin_amdgcn_sched_barrier(0);
    };

    // W fragment base for this u + lane's 16B slot (bf16, MFMA-fragment order)
    const short* WgU = (const short*)Wc + (size_t)u * 98304 + lane * 8;

    // ---- prologue -----------------------------------------------------------
    ISSUE(r0);
    WRITE(0);
    ISSUE(r0 + 32);
    BARRIER();

    #pragma unroll 1
    for (int j = 0; j < 4; ++j) {
        const int buf = j & 1;

        // ---- compute tile j: stream W frags from L2, X frags from LDS -------
        floatx4 aR[2]  = {accR0,  accR0};
        floatx4 aZ[2]  = {accZ0,  accZ0};
        floatx4 aXN[2] = {accXN0, accXN0};
        floatx4 aHN[2] = {accHN0, accHN0};
        #pragma unroll
        for (int s = 0; s < 8; ++s) {
            short8 bR = *(const short8*)(WgU + (size_t)(      wv * 8 + s) * 512);
            short8 bZ = *(const short8*)(WgU + (size_t)( 64 + wv * 8 + s) * 512);
            short8 bN = *(const short8*)(WgU + (size_t)(128 + wv * 8 + s) * 512);
            #pragma unroll
            for (int m4 = 0; m4 < 2; ++m4) {
                short8 xF = *(const short8*)((const short*)&Xs[buf][m4 * 16 + lr][0]
                                             + s * 32 + lq * 8);
                aR[m4] = MFMA16(bR, xF, aR[m4]);
                aZ[m4] = MFMA16(bZ, xF, aZ[m4]);
                if (s < 4) aXN[m4] = MFMA16(bN, xF, aXN[m4]);
                else       aHN[m4] = MFMA16(bN, xF, aHN[m4]);
            }
        }

        // ---- pipeline: land tile j+1, launch tile j+2 -----------------------
        if (j < 3) {
            WRITE(buf ^ 1);                       // waits only its own stg vmcnt
            if (j < 2) ISSUE(r0 + (j + 2) * 32);  // fire-and-forget
        }

        // ---- gate math in regs (hv read from Xs[buf] BEFORE it is reused) ---
        floatx4 o[2];
        #pragma unroll
        for (int m4 = 0; m4 < 2; ++m4) {
            const int mloc = m4 * 16 + lr;
            ushort4 hq = *(const ushort4*)&Xs[buf][mloc][128 + c0];
            const unsigned short hs[4] = {hq.x, hq.y, hq.z, hq.w};
            #pragma unroll
            for (int r = 0; r < 4; ++r) {
                float rv = __builtin_amdgcn_rcpf(1.f + __expf(-aR[m4][r]));
                float zv = __builtin_amdgcn_rcpf(1.f + __expf(-aZ[m4][r]));
                float npre = aXN[m4][r] + rv * aHN[m4][r];
                float nv = 2.f * __builtin_amdgcn_rcpf(1.f + __expf(-2.f * npre)) - 1.f; // tanh
                float hv = bf2f(hs[r]);          // original hidden (bf16, LDS)
                o[m4][r] = nv + zv * (hv - nv);
            }
        }

        BARRIER();   // all waves done reading Xs[buf] (MFMA frags + hv)

        // ---- bounce: fp32 results into dead Xs[buf] (view [32][FPAD]) -------
        float* Fv = (float*)&Xs[buf][0][0];
        #pragma unroll
        for (int m4 = 0; m4 < 2; ++m4)
            *(floatx4*)&Fv[(m4 * 16 + lr) * FPAD + c0] = o[m4];

        BARRIER();   // fp32 tile visible to all waves

        // ---- store pass: each wave writes full 512B rows (full 128B lines) --
        const int rowb = r0 + j * 32;
        #pragma unroll
        for (int p = 0; p < 2; ++p) {
            const int row = p * 16 + (tid >> 5);
            const int col = (tid & 31) * 4;
            floatx4 v = *(const floatx4*)&Fv[row * FPAD + col];
            __builtin_nontemporal_store(
                v, (floatx4*)(out + (size_t)(rowb + row) * UH + u * 128 + col));
        }

        if (j < 3) BARRIER();   // store-pass reads done before WRITE(buf) next iter
    }
}

// ---------------- launch ------------------------------------------------------

extern "C" void kernel_launch(void* const* d_in, const int* in_sizes, int n_in,
                              void* d_out, int out_size, void* d_ws, size_t ws_size,
                              hipStream_t stream) {
    const float* inputs = (const float*)d_in[0];
    const float* hidden = (const float*)d_in[1];
    const float* w_ih   = (const float*)d_in[2];
    const float* w_hh   = (const float*)d_in[3];
    const float* b_ih   = (const float*)d_in[4];
    const float* b_hh   = (const float*)d_in[5];
    float* out = (float*)d_out;

    __hip_bfloat16* Wc = (__hip_bfloat16*)d_ws;
    float* bias_c = (float*)((char*)d_ws + (size_t)16 * 384 * 256 * 2);  // +3,145,728 B

    prep<<<dim3(800), dim3(256), 0, stream>>>(w_ih, w_hh, b_ih, b_hh, Wc, bias_c);
    gru_fused<<<dim3(1024), dim3(512), 0, stream>>>(inputs, hidden, Wc, bias_c, out);
}